// Round 7
// baseline (162.005 us; speedup 1.0000x reference)
//
#include <hip/hip_runtime.h>
#include <stdint.h>

typedef unsigned short u16;
typedef float f32x4 __attribute__((ext_vector_type(4)));
typedef __bf16 bf16x8 __attribute__((ext_vector_type(8)));

#define DDIM 768
#define NHEAD 12
#define EDIM 64
#define SREAL 2000
#define SPAD 2048
#define NQ 2048
#define NSPLIT 4

__device__ __forceinline__ u16 f2bf(float f) {
    unsigned u = __float_as_uint(f);
    return (u16)((u + 0x7fffu + ((u >> 16) & 1u)) >> 16);
}
__device__ __forceinline__ float bf2f(u16 v) {
    return __uint_as_float(((unsigned)v) << 16);
}

__device__ __forceinline__ void async16(const void* g, void* l) {
    __builtin_amdgcn_global_load_lds(
        (const __attribute__((address_space(1))) void*)(const void*)g,
        (__attribute__((address_space(3))) void*)l, 16, 0, 0);
}

// ---------------- fused: cast weights -> bf16 (Wq pre-scaled by 0.125, incl. Wo) + layernorm ----------------
__global__ __launch_bounds__(256) void prep_kernel(
    const float* __restrict__ Wq, const float* __restrict__ Wk, const float* __restrict__ Wv,
    const float* __restrict__ Wo,
    u16* __restrict__ Wqb, u16* __restrict__ Wkb, u16* __restrict__ Wvb, u16* __restrict__ Wob,
    const float* __restrict__ tgt, const float* __restrict__ keyb, const float* __restrict__ valb,
    const float* __restrict__ g_q, const float* __restrict__ b_q,
    const float* __restrict__ g_kv, const float* __restrict__ b_kv,
    u16* __restrict__ lnQ, u16* __restrict__ lnK, u16* __restrict__ lnV)
{
    int bx = blockIdx.x;
    if (bx < 2304) {
        int g = bx * 256 + threadIdx.x;   // float4 index, total 4*147456
        const float* src; u16* dst; int idx; float sc = 1.f;
        if (g < 147456)      { src = Wq; dst = Wqb; idx = g; sc = 0.125f; }
        else if (g < 294912) { src = Wk; dst = Wkb; idx = g - 147456; }
        else if (g < 442368) { src = Wv; dst = Wvb; idx = g - 294912; }
        else                 { src = Wo; dst = Wob; idx = g - 442368; }
        f32x4 a = ((const f32x4*)src)[idx];
        ushort4 o;
        o.x = f2bf(a[0] * sc); o.y = f2bf(a[1] * sc);
        o.z = f2bf(a[2] * sc); o.w = f2bf(a[3] * sc);
        ((ushort4*)dst)[idx] = o;
        return;
    }
    int row = (bx - 2304) * 4 + (threadIdx.x >> 6);
    int l = threadIdx.x & 63;
    const float* src = nullptr; const float* gg; const float* bb; u16* dst;
    bool zero = false;
    if (row < 2048) {
        src = tgt + (size_t)row * DDIM; gg = g_q; bb = b_q; dst = lnQ + (size_t)row * DDIM;
    } else if (row < 4096) {
        int r = row - 2048; gg = g_kv; bb = b_kv; dst = lnK + (size_t)r * DDIM;
        if (r < SREAL) src = keyb + (size_t)r * DDIM; else zero = true;
    } else {
        int r = row - 4096; gg = g_kv; bb = b_kv; dst = lnV + (size_t)r * DDIM;
        if (r < SREAL) src = valb + (size_t)r * DDIM; else zero = true;
    }
    if (zero) {
        ushort4 z; z.x = 0; z.y = 0; z.z = 0; z.w = 0;
#pragma unroll
        for (int i = 0; i < 3; i++) ((ushort4*)dst)[l + 64 * i] = z;
        return;
    }
    f32x4 a[3];
#pragma unroll
    for (int i = 0; i < 3; i++) a[i] = ((const f32x4*)src)[l + 64 * i];
    float s = 0.f;
#pragma unroll
    for (int i = 0; i < 3; i++) { s += a[i][0] + a[i][1] + a[i][2] + a[i][3]; }
#pragma unroll
    for (int m = 1; m < 64; m <<= 1) s += __shfl_xor(s, m, 64);
    float mean = s * (1.f / 768.f);
    float v = 0.f;
#pragma unroll
    for (int i = 0; i < 3; i++)
#pragma unroll
        for (int j = 0; j < 4; j++) { float d = a[i][j] - mean; v += d * d; }
#pragma unroll
    for (int m = 1; m < 64; m <<= 1) v += __shfl_xor(v, m, 64);
    float rstd = rsqrtf(v * (1.f / 768.f) + 1e-5f);
#pragma unroll
    for (int i = 0; i < 3; i++) {
        f32x4 g4 = ((const f32x4*)gg)[l + 64 * i];
        f32x4 b4 = ((const f32x4*)bb)[l + 64 * i];
        ushort4 o;
        o.x = f2bf((a[i][0] - mean) * rstd * g4[0] + b4[0]);
        o.y = f2bf((a[i][1] - mean) * rstd * g4[1] + b4[1]);
        o.z = f2bf((a[i][2] - mean) * rstd * g4[2] + b4[2]);
        o.w = f2bf((a[i][3] - mean) * rstd * g4[3] + b4[3]);
        ((ushort4*)dst)[l + 64 * i] = o;
    }
}

// ---------------- batched projection GEMM: C = A(M,768) @ W(768,768)^T + bias ----------------
// 128m x 64n tile, BK=64 double-buffered, 576 blocks (2.25/CU).
// z==2 (V) epilogue: C^T staged through LDS (reusing Ash), then 256B-contiguous row stores.
__global__ __launch_bounds__(256) void proj_kernel(
    const u16* __restrict__ lnQ, const u16* __restrict__ lnK, const u16* __restrict__ lnV,
    const u16* __restrict__ Wqb, const u16* __restrict__ Wkb, const u16* __restrict__ Wvb,
    const float* __restrict__ bq, const float* __restrict__ bk, const float* __restrict__ bv,
    u16* __restrict__ Qm, u16* __restrict__ Km, u16* __restrict__ VmT)
{
    __shared__ u16 Ash[2][128 * 64];
    __shared__ u16 Bsh[2][64 * 64];
    const u16* A; const u16* W; const float* bias; float bscale; int z = blockIdx.z;
    if (z == 0)      { A = lnQ; W = Wqb; bias = bq; bscale = 0.125f; }
    else if (z == 1) { A = lnK; W = Wkb; bias = bk; bscale = 1.f; }
    else             { A = lnV; W = Wvb; bias = bv; bscale = 1.f; }
    int n0 = blockIdx.x * 64, m0 = blockIdx.y * 128;
    int t = threadIdx.x, l = t & 63, quad = l >> 4, c16 = l & 15;
    int w = t >> 6;

    f32x4 acc[2][4];
    f32x4 zz = {0.f, 0.f, 0.f, 0.f};
#pragma unroll
    for (int mi = 0; mi < 2; mi++)
#pragma unroll
        for (int ni = 0; ni < 4; ni++) acc[mi][ni] = zz;

#pragma unroll
    for (int i = 0; i < 4; i++) {
        int ch = i * 256 + t;
        int r = ch >> 3, pc = ch & 7, jc = pc ^ (r & 7);
        async16(A + (size_t)(m0 + r) * DDIM + jc * 8, (char*)Ash[0] + ch * 16);
    }
#pragma unroll
    for (int i = 0; i < 2; i++) {
        int ch = i * 256 + t;
        int r = ch >> 3, pc = ch & 7, jc = pc ^ (r & 7);
        async16(W + (size_t)(n0 + r) * DDIM + jc * 8, (char*)Bsh[0] + ch * 16);
    }
    for (int kt = 0; kt < 12; kt++) {
        int cur = kt & 1;
        __syncthreads();
        if (kt < 11) {
            int k0 = (kt + 1) * 64;
#pragma unroll
            for (int i = 0; i < 4; i++) {
                int ch = i * 256 + t;
                int r = ch >> 3, pc = ch & 7, jc = pc ^ (r & 7);
                async16(A + (size_t)(m0 + r) * DDIM + k0 + jc * 8, (char*)Ash[cur ^ 1] + ch * 16);
            }
#pragma unroll
            for (int i = 0; i < 2; i++) {
                int ch = i * 256 + t;
                int r = ch >> 3, pc = ch & 7, jc = pc ^ (r & 7);
                async16(W + (size_t)(n0 + r) * DDIM + k0 + jc * 8, (char*)Bsh[cur ^ 1] + ch * 16);
            }
        }
#pragma unroll
        for (int kk = 0; kk < 2; kk++) {
            bf16x8 a[2], b[4];
#pragma unroll
            for (int mi = 0; mi < 2; mi++) {
                int row = w * 32 + mi * 16 + c16;
                int p = (kk * 4 + quad) ^ (row & 7);
                a[mi] = *(const bf16x8*)(Ash[cur] + row * 64 + p * 8);
            }
#pragma unroll
            for (int ni = 0; ni < 4; ni++) {
                int row = ni * 16 + c16;
                int p = (kk * 4 + quad) ^ (row & 7);
                b[ni] = *(const bf16x8*)(Bsh[cur] + row * 64 + p * 8);
            }
#pragma unroll
            for (int mi = 0; mi < 2; mi++)
#pragma unroll
                for (int ni = 0; ni < 4; ni++)
                    acc[mi][ni] = __builtin_amdgcn_mfma_f32_16x16x32_bf16(a[mi], b[ni], acc[mi][ni], 0, 0, 0);
        }
        __syncthreads();
    }
    if (z < 2) {
        u16* out = (z == 0) ? Qm : Km;
        int Mact = (z == 0) ? NQ : SREAL;
#pragma unroll
        for (int mi = 0; mi < 2; mi++)
#pragma unroll
            for (int ni = 0; ni < 4; ni++) {
                int n = n0 + ni * 16 + c16;
                float bval = bias[n] * bscale;
#pragma unroll
                for (int r = 0; r < 4; r++) {
                    int m = m0 + w * 32 + mi * 16 + quad * 4 + r;
                    float val = (m < Mact) ? (acc[mi][ni][r] + bval) : 0.f;
                    out[(size_t)m * DDIM + n] = f2bf(val);
                }
            }
    } else {
        // C^T via LDS: Csh[64 n][128 m], padded stride 136 u16 (8-aligned, conflict-light).
        u16* Csh = (u16*)Ash;   // Ash dead after the K-loop; 64*136*2 = 17408 B < 32 KiB
        const int CP = 136;
#pragma unroll
        for (int mi = 0; mi < 2; mi++)
#pragma unroll
            for (int ni = 0; ni < 4; ni++) {
                int n = n0 + ni * 16 + c16;
                float bval = bias[n];
                int lm = w * 32 + mi * 16 + quad * 4;
                int mg = m0 + lm;
                ushort4 o;
                o.x = (mg + 0 < SREAL) ? f2bf(acc[mi][ni][0] + bval) : (u16)0;
                o.y = (mg + 1 < SREAL) ? f2bf(acc[mi][ni][1] + bval) : (u16)0;
                o.z = (mg + 2 < SREAL) ? f2bf(acc[mi][ni][2] + bval) : (u16)0;
                o.w = (mg + 3 < SREAL) ? f2bf(acc[mi][ni][3] + bval) : (u16)0;
                *(ushort4*)(Csh + (ni * 16 + c16) * CP + lm) = o;
            }
        __syncthreads();
        // 64 rows x 256 B contiguous stores: 1024 16B chunks over 256 threads
#pragma unroll
        for (int i = 0; i < 4; i++) {
            int ch = i * 256 + t;
            int n = ch >> 4, c = ch & 15;
            uint4 v = *(const uint4*)(Csh + n * CP + c * 8);
            *(uint4*)(VmT + (size_t)(n0 + n) * SPAD + m0 + c * 8) = v;
        }
    }
}

// ---------------- split-S flash attention, no-max softmax, 64-s chunks ----------------
__global__ __launch_bounds__(256, 4) void attn_kernel(
    const u16* __restrict__ Qm, const u16* __restrict__ Km, const u16* __restrict__ VmT,
    const int* __restrict__ bank_mask,
    u16* __restrict__ Opart, float* __restrict__ Lpart)
{
    __shared__ __align__(16) u16 SH[64 * 64 * 3];   // K | V^T | P
    __shared__ float mk[64];
    u16* Ksh = SH;
    u16* Vsh = SH + 4096;
    u16* Psh = SH + 8192;
    int b = blockIdx.x;
    int xcd = b & 7, j = b >> 3;
    int grp = xcd * 6 + (j >> 5);         // grp = sp*NHEAD + h
    int qt = j & 31;
    int sp = grp / NHEAD, h = grp - sp * NHEAD;
    int q0 = qt * 64;
    int t = threadIdx.x, w = t >> 6, l = t & 63, quad = l >> 4, c16 = l & 15;

    bf16x8 qf[2];
#pragma unroll
    for (int kk = 0; kk < 2; kk++) {
        int row = q0 + w * 16 + c16;
        qf[kk] = *(const bf16x8*)(Qm + (size_t)row * DDIM + h * EDIM + kk * 32 + quad * 8);
    }
    bf16x8 ones;
#pragma unroll
    for (int i = 0; i < 8; i++) ones[i] = (__bf16)1.0f;

    f32x4 zz = {0.f, 0.f, 0.f, 0.f};
    f32x4 of[4], ol;
#pragma unroll
    for (int nei = 0; nei < 4; nei++) of[nei] = zz;
    ol = zz;

    for (int sc = 0; sc < 8; sc++) {
        int s0 = sp * 512 + sc * 64;
#pragma unroll
        for (int i = 0; i < 2; i++) {
            int ch = i * 256 + t;
            int r = ch >> 3, pc = ch & 7, jc = pc ^ (r & 7);
            async16(Km + (size_t)(s0 + r) * DDIM + h * EDIM + jc * 8, (char*)Ksh + ch * 16);
        }
#pragma unroll
        for (int i = 0; i < 2; i++) {
            int ch = i * 256 + t;
            int e = ch >> 3, pc = ch & 7, jc = pc ^ (e & 7);
            async16(VmT + (size_t)(h * EDIM + e) * SPAD + s0 + jc * 8, (char*)Vsh + ch * 16);
        }
        if (t < 64) {
            int s = s0 + t;
            mk[t] = (s < SREAL && bank_mask[s] != 0) ? 1.f : 0.f;
        }
        __syncthreads();

        f32x4 sacc[4];
#pragma unroll
        for (int ni = 0; ni < 4; ni++) sacc[ni] = zz;
#pragma unroll
        for (int kk = 0; kk < 2; kk++) {
            bf16x8 kb[4];
#pragma unroll
            for (int ni = 0; ni < 4; ni++) {
                int row = ni * 16 + c16;
                int p = (kk * 4 + quad) ^ (row & 7);
                kb[ni] = *(const bf16x8*)(Ksh + row * 64 + p * 8);
            }
#pragma unroll
            for (int ni = 0; ni < 4; ni++)
                sacc[ni] = __builtin_amdgcn_mfma_f32_16x16x32_bf16(qf[kk], kb[ni], sacc[ni], 0, 0, 0);
        }
        float m01[4];
#pragma unroll
        for (int ni = 0; ni < 4; ni++) m01[ni] = mk[ni * 16 + c16];
#pragma unroll
        for (int ni = 0; ni < 4; ni++)
#pragma unroll
            for (int r = 0; r < 4; r++)
                sacc[ni][r] = __expf(sacc[ni][r]) * m01[ni];

#pragma unroll
        for (int ni = 0; ni < 4; ni++)
#pragma unroll
            for (int r = 0; r < 4; r++) {
                int row = w * 16 + quad * 4 + r;
                int col = ni * 16 + c16;
                int p = (col >> 3) ^ (row & 7);
                Psh[row * 64 + p * 8 + (col & 7)] = f2bf(sacc[ni][r]);
            }

#pragma unroll
        for (int kk = 0; kk < 2; kk++) {
            bf16x8 pa, vb[4];
            {
                int row = w * 16 + c16;
                int p = (kk * 4 + quad) ^ (row & 7);
                pa = *(const bf16x8*)(Psh + row * 64 + p * 8);
            }
#pragma unroll
            for (int nei = 0; nei < 4; nei++) {
                int e = nei * 16 + c16;
                int p = (kk * 4 + quad) ^ (e & 7);
                vb[nei] = *(const bf16x8*)(Vsh + e * 64 + p * 8);
            }
#pragma unroll
            for (int nei = 0; nei < 4; nei++)
                of[nei] = __builtin_amdgcn_mfma_f32_16x16x32_bf16(pa, vb[nei], of[nei], 0, 0, 0);
            ol = __builtin_amdgcn_mfma_f32_16x16x32_bf16(pa, ones, ol, 0, 0, 0);
        }
        __syncthreads();
    }

    // epilogue: transpose O through LDS (per-wave slice), store coalesced bf16
    float* Ost = (float*)SH + w * (16 * 68);
#pragma unroll
    for (int nei = 0; nei < 4; nei++)
#pragma unroll
        for (int r = 0; r < 4; r++)
            Ost[(quad * 4 + r) * 68 + nei * 16 + c16] = of[nei][r];
    int qq = l >> 2, cc = (l & 3) ^ (qq & 3);
    int base = grp * 32 + qt;
    uint4 packed[2];
    u16* pk = (u16*)packed;
#pragma unroll
    for (int jj = 0; jj < 4; jj++) {
        f32x4 v = *(const f32x4*)(Ost + qq * 68 + cc * 16 + jj * 4);
        pk[jj * 4 + 0] = f2bf(v[0]); pk[jj * 4 + 1] = f2bf(v[1]);
        pk[jj * 4 + 2] = f2bf(v[2]); pk[jj * 4 + 3] = f2bf(v[3]);
    }
    {
        u16* dst = Opart + (size_t)base * 4096 + (w * 16 + qq) * 64 + cc * 16;
        *(uint4*)dst = packed[0];
        *(uint4*)(dst + 8) = packed[1];
    }
    if (c16 == 0) {
#pragma unroll
        for (int r = 0; r < 4; r++) {
            int rin = w * 16 + quad * 4 + r;
            Lpart[(size_t)base * 64 + rin] = ol[r];
        }
    }
}

// ---------------- combine partials + mean-pool over TQ -> pooled (bf16), 4-wide ----------------
__global__ __launch_bounds__(256) void combine_kernel(
    const u16* __restrict__ Opart, const float* __restrict__ Lpart,
    u16* __restrict__ pooledb)
{
    int t = threadIdx.x;
    int gi = blockIdx.x * 16 + (t >> 4);   // 0..3071
    int e0 = (t & 15) * 4;
    int lq = gi / NHEAD, h = gi - lq * NHEAD;
    float a0 = 0.f, a1 = 0.f, a2 = 0.f, a3 = 0.f;
#pragma unroll
    for (int row = 0; row < 8; row++) {
        int qrow = lq * 8 + row;
        int qt = qrow >> 6, rin = qrow & 63;
        float Ls = 0.f, v0 = 0.f, v1 = 0.f, v2 = 0.f, v3 = 0.f;
#pragma unroll
        for (int sp = 0; sp < NSPLIT; sp++) {
            int base = (sp * NHEAD + h) * 32 + qt;
            Ls += Lpart[(size_t)base * 64 + rin];
            ushort4 o4 = *(const ushort4*)(Opart + (size_t)base * 4096 + rin * 64 + e0);
            v0 += bf2f(o4.x); v1 += bf2f(o4.y); v2 += bf2f(o4.z); v3 += bf2f(o4.w);
        }
        a0 += v0 / Ls; a1 += v1 / Ls; a2 += v2 / Ls; a3 += v3 / Ls;
    }
    ushort4 o;
    o.x = f2bf(a0 * 0.125f); o.y = f2bf(a1 * 0.125f);
    o.z = f2bf(a2 * 0.125f); o.w = f2bf(a3 * 0.125f);
    *(ushort4*)(pooledb + (size_t)lq * DDIM + h * EDIM + e0) = o;
}

// ---------------- final GEMM y = pooled(256,768) @ Wo(768,768)^T + bo, bf16 MFMA ----------------
// BK=128 double-buffered (48 blocks -> LDS is free; hides per-step L2 latency).
__global__ __launch_bounds__(256) void wo_kernel(
    const u16* __restrict__ pb, const u16* __restrict__ Wob,
    const float* __restrict__ bo, float* __restrict__ y)
{
    __shared__ u16 Ash[2][64 * 128];
    __shared__ u16 Bsh[2][64 * 128];
    int m0 = blockIdx.x * 64, n0 = blockIdx.y * 64;
    int t = threadIdx.x, w = t >> 6, l = t & 63, quad = l >> 4, c16 = l & 15;

    f32x4 acc[4];
    f32x4 zz = {0.f, 0.f, 0.f, 0.f};
#pragma unroll
    for (int ni = 0; ni < 4; ni++) acc[ni] = zz;

#pragma unroll
    for (int i = 0; i < 4; i++) {
        int ch = i * 256 + t;
        int r = ch >> 4, pc = ch & 15, jc = pc ^ (r & 15);
        async16(pb + (size_t)(m0 + r) * DDIM + jc * 8, (char*)Ash[0] + ch * 16);
        async16(Wob + (size_t)(n0 + r) * DDIM + jc * 8, (char*)Bsh[0] + ch * 16);
    }
    for (int kt = 0; kt < 6; kt++) {
        int cur = kt & 1;
        __syncthreads();
        if (kt < 5) {
            int k0 = (kt + 1) * 128;
#pragma unroll
            for (int i = 0; i < 4; i++) {
                int ch = i * 256 + t;
                int r = ch >> 4, pc = ch & 15, jc = pc ^ (r & 15);
                async16(pb + (size_t)(m0 + r) * DDIM + k0 + jc * 8, (char*)Ash[cur ^ 1] + ch * 16);
                async16(Wob + (size_t)(n0 + r) * DDIM + k0 + jc * 8, (char*)Bsh[cur ^ 1] + ch * 16);
            }
        }
#pragma unroll
        for (int kk = 0; kk < 4; kk++) {
            int p = (kk * 4 + quad) ^ c16;
            bf16x8 a = *(const bf16x8*)(Ash[cur] + (w * 16 + c16) * 128 + p * 8);
            bf16x8 b[4];
#pragma unroll
            for (int ni = 0; ni < 4; ni++)
                b[ni] = *(const bf16x8*)(Bsh[cur] + (ni * 16 + c16) * 128 + p * 8);
#pragma unroll
            for (int ni = 0; ni < 4; ni++)
                acc[ni] = __builtin_amdgcn_mfma_f32_16x16x32_bf16(a, b[ni], acc[ni], 0, 0, 0);
        }
        __syncthreads();
    }
#pragma unroll
    for (int ni = 0; ni < 4; ni++) {
        int n = n0 + ni * 16 + c16;
        float bval = bo[n];
#pragma unroll
        for (int r = 0; r < 4; r++) {
            int m = m0 + w * 16 + quad * 4 + r;
            y[(size_t)m * DDIM + n] = acc[ni][r] + bval;
        }
    }
}

extern "C" void kernel_launch(void* const* d_in, const int* in_sizes, int n_in,
                              void* d_out, int out_size, void* d_ws, size_t ws_size,
                              hipStream_t stream)
{
    const float* tgt     = (const float*)d_in[0];
    const float* keyb    = (const float*)d_in[1];
    const float* valb    = (const float*)d_in[2];
    const int*   mask    = (const int*)d_in[3];
    const float* Wq      = (const float*)d_in[4];
    const float* bq      = (const float*)d_in[5];
    const float* Wk      = (const float*)d_in[6];
    const float* bk      = (const float*)d_in[7];
    const float* Wv      = (const float*)d_in[8];
    const float* bv      = (const float*)d_in[9];
    const float* Wo      = (const float*)d_in[10];
    const float* bo      = (const float*)d_in[11];
    const float* g_q     = (const float*)d_in[12];
    const float* beta_q  = (const float*)d_in[13];
    const float* g_kv    = (const float*)d_in[14];
    const float* beta_kv = (const float*)d_in[15];
    float* y = (float*)d_out;

    char* ws = (char*)d_ws;
    // persistent:
    u16* Qm  = (u16*)(ws + 0);           // 3,145,728
    u16* Km  = (u16*)(ws + 3145728);     // 3,145,728
    u16* VmT = (u16*)(ws + 6291456);     // 3,145,728
    u16* Wob = (u16*)(ws + 9437184);     // 1,179,648
    // phase A (dead after proj_kernel):
    u16* lnQ = (u16*)(ws + 10616832);
    u16* lnK = (u16*)(ws + 13762560);
    u16* lnV = (u16*)(ws + 16908288);
    u16* Wqb = (u16*)(ws + 20054016);
    u16* Wkb = (u16*)(ws + 21233664);
    u16* Wvb = (u16*)(ws + 22413312);    // ends 23,592,960
    // phase B (aliases phase A region):
    u16*   Opart   = (u16*)(ws + 10616832);   // 12,582,912 -> ends 23,199,744
    float* Lpart   = (float*)(ws + 23592960); // 393,216
    u16*   pooledb = (u16*)(ws + 23986176);   // 393,216

    hipLaunchKernelGGL(prep_kernel, dim3(3840), dim3(256), 0, stream,
                       Wq, Wk, Wv, Wo, Wqb, Wkb, Wvb, Wob,
                       tgt, keyb, valb, g_q, beta_q, g_kv, beta_kv, lnQ, lnK, lnV);
    hipLaunchKernelGGL(proj_kernel, dim3(12, 16, 3), dim3(256), 0, stream,
                       lnQ, lnK, lnV, Wqb, Wkb, Wvb, bq, bk, bv, Qm, Km, VmT);
    hipLaunchKernelGGL(attn_kernel, dim3(1536), dim3(256), 0, stream,
                       Qm, Km, VmT, mask, Opart, Lpart);
    hipLaunchKernelGGL(combine_kernel, dim3(192), dim3(256), 0, stream,
                       Opart, Lpart, pooledb);
    hipLaunchKernelGGL(wo_kernel, dim3(4, 12), dim3(256), 0, stream,
                       pooledb, Wob, bo, y);
}

// Round 8
// 159.413 us; speedup vs baseline: 1.0163x; 1.0163x over previous
//
#include <hip/hip_runtime.h>
#include <stdint.h>

typedef unsigned short u16;
typedef float f32x4 __attribute__((ext_vector_type(4)));
typedef __bf16 bf16x8 __attribute__((ext_vector_type(8)));

#define DDIM 768
#define NHEAD 12
#define EDIM 64
#define SREAL 2000
#define SPAD 2048
#define NQ 2048
#define NSPLIT 4

__device__ __forceinline__ u16 f2bf(float f) {
    unsigned u = __float_as_uint(f);
    return (u16)((u + 0x7fffu + ((u >> 16) & 1u)) >> 16);
}
__device__ __forceinline__ float bf2f(u16 v) {
    return __uint_as_float(((unsigned)v) << 16);
}

__device__ __forceinline__ void async16(const void* g, void* l) {
    __builtin_amdgcn_global_load_lds(
        (const __attribute__((address_space(1))) void*)(const void*)g,
        (__attribute__((address_space(3))) void*)l, 16, 0, 0);
}

// ---------------- fused: cast weights -> bf16 (Wq pre-scaled by 0.125, incl. Wo) + layernorm ----------------
__global__ __launch_bounds__(256) void prep_kernel(
    const float* __restrict__ Wq, const float* __restrict__ Wk, const float* __restrict__ Wv,
    const float* __restrict__ Wo,
    u16* __restrict__ Wqb, u16* __restrict__ Wkb, u16* __restrict__ Wvb, u16* __restrict__ Wob,
    const float* __restrict__ tgt, const float* __restrict__ keyb, const float* __restrict__ valb,
    const float* __restrict__ g_q, const float* __restrict__ b_q,
    const float* __restrict__ g_kv, const float* __restrict__ b_kv,
    u16* __restrict__ lnQ, u16* __restrict__ lnK, u16* __restrict__ lnV)
{
    int bx = blockIdx.x;
    if (bx < 2304) {
        int g = bx * 256 + threadIdx.x;   // float4 index, total 4*147456
        const float* src; u16* dst; int idx; float sc = 1.f;
        if (g < 147456)      { src = Wq; dst = Wqb; idx = g; sc = 0.125f; }
        else if (g < 294912) { src = Wk; dst = Wkb; idx = g - 147456; }
        else if (g < 442368) { src = Wv; dst = Wvb; idx = g - 294912; }
        else                 { src = Wo; dst = Wob; idx = g - 442368; }
        f32x4 a = ((const f32x4*)src)[idx];
        ushort4 o;
        o.x = f2bf(a[0] * sc); o.y = f2bf(a[1] * sc);
        o.z = f2bf(a[2] * sc); o.w = f2bf(a[3] * sc);
        ((ushort4*)dst)[idx] = o;
        return;
    }
    int row = (bx - 2304) * 4 + (threadIdx.x >> 6);
    int l = threadIdx.x & 63;
    const float* src = nullptr; const float* gg; const float* bb; u16* dst;
    bool zero = false;
    if (row < 2048) {
        src = tgt + (size_t)row * DDIM; gg = g_q; bb = b_q; dst = lnQ + (size_t)row * DDIM;
    } else if (row < 4096) {
        int r = row - 2048; gg = g_kv; bb = b_kv; dst = lnK + (size_t)r * DDIM;
        if (r < SREAL) src = keyb + (size_t)r * DDIM; else zero = true;
    } else {
        int r = row - 4096; gg = g_kv; bb = b_kv; dst = lnV + (size_t)r * DDIM;
        if (r < SREAL) src = valb + (size_t)r * DDIM; else zero = true;
    }
    if (zero) {
        ushort4 z; z.x = 0; z.y = 0; z.z = 0; z.w = 0;
#pragma unroll
        for (int i = 0; i < 3; i++) ((ushort4*)dst)[l + 64 * i] = z;
        return;
    }
    f32x4 a[3];
#pragma unroll
    for (int i = 0; i < 3; i++) a[i] = ((const f32x4*)src)[l + 64 * i];
    float s = 0.f;
#pragma unroll
    for (int i = 0; i < 3; i++) { s += a[i][0] + a[i][1] + a[i][2] + a[i][3]; }
#pragma unroll
    for (int m = 1; m < 64; m <<= 1) s += __shfl_xor(s, m, 64);
    float mean = s * (1.f / 768.f);
    float v = 0.f;
#pragma unroll
    for (int i = 0; i < 3; i++)
#pragma unroll
        for (int j = 0; j < 4; j++) { float d = a[i][j] - mean; v += d * d; }
#pragma unroll
    for (int m = 1; m < 64; m <<= 1) v += __shfl_xor(v, m, 64);
    float rstd = rsqrtf(v * (1.f / 768.f) + 1e-5f);
#pragma unroll
    for (int i = 0; i < 3; i++) {
        f32x4 g4 = ((const f32x4*)gg)[l + 64 * i];
        f32x4 b4 = ((const f32x4*)bb)[l + 64 * i];
        ushort4 o;
        o.x = f2bf((a[i][0] - mean) * rstd * g4[0] + b4[0]);
        o.y = f2bf((a[i][1] - mean) * rstd * g4[1] + b4[1]);
        o.z = f2bf((a[i][2] - mean) * rstd * g4[2] + b4[2]);
        o.w = f2bf((a[i][3] - mean) * rstd * g4[3] + b4[3]);
        ((ushort4*)dst)[l + 64 * i] = o;
    }
}

// ---------------- batched projection GEMM: C = A(M,768) @ W(768,768)^T + bias ----------------
// 128m x 64n tile, BK=64 double-buffered, 576 blocks (2.25/CU).
__global__ __launch_bounds__(256) void proj_kernel(
    const u16* __restrict__ lnQ, const u16* __restrict__ lnK, const u16* __restrict__ lnV,
    const u16* __restrict__ Wqb, const u16* __restrict__ Wkb, const u16* __restrict__ Wvb,
    const float* __restrict__ bq, const float* __restrict__ bk, const float* __restrict__ bv,
    u16* __restrict__ Qm, u16* __restrict__ Km, u16* __restrict__ VmT)
{
    __shared__ u16 Ash[2][128 * 64];
    __shared__ u16 Bsh[2][64 * 64];
    const u16* A; const u16* W; const float* bias; float bscale; int z = blockIdx.z;
    if (z == 0)      { A = lnQ; W = Wqb; bias = bq; bscale = 0.125f; }
    else if (z == 1) { A = lnK; W = Wkb; bias = bk; bscale = 1.f; }
    else             { A = lnV; W = Wvb; bias = bv; bscale = 1.f; }
    int n0 = blockIdx.x * 64, m0 = blockIdx.y * 128;
    int t = threadIdx.x, l = t & 63, quad = l >> 4, c16 = l & 15;
    int w = t >> 6;

    f32x4 acc[2][4];
    f32x4 zz = {0.f, 0.f, 0.f, 0.f};
#pragma unroll
    for (int mi = 0; mi < 2; mi++)
#pragma unroll
        for (int ni = 0; ni < 4; ni++) acc[mi][ni] = zz;

#pragma unroll
    for (int i = 0; i < 4; i++) {
        int ch = i * 256 + t;
        int r = ch >> 3, pc = ch & 7, jc = pc ^ (r & 7);
        async16(A + (size_t)(m0 + r) * DDIM + jc * 8, (char*)Ash[0] + ch * 16);
    }
#pragma unroll
    for (int i = 0; i < 2; i++) {
        int ch = i * 256 + t;
        int r = ch >> 3, pc = ch & 7, jc = pc ^ (r & 7);
        async16(W + (size_t)(n0 + r) * DDIM + jc * 8, (char*)Bsh[0] + ch * 16);
    }
    for (int kt = 0; kt < 12; kt++) {
        int cur = kt & 1;
        __syncthreads();
        if (kt < 11) {
            int k0 = (kt + 1) * 64;
#pragma unroll
            for (int i = 0; i < 4; i++) {
                int ch = i * 256 + t;
                int r = ch >> 3, pc = ch & 7, jc = pc ^ (r & 7);
                async16(A + (size_t)(m0 + r) * DDIM + k0 + jc * 8, (char*)Ash[cur ^ 1] + ch * 16);
            }
#pragma unroll
            for (int i = 0; i < 2; i++) {
                int ch = i * 256 + t;
                int r = ch >> 3, pc = ch & 7, jc = pc ^ (r & 7);
                async16(W + (size_t)(n0 + r) * DDIM + k0 + jc * 8, (char*)Bsh[cur ^ 1] + ch * 16);
            }
        }
#pragma unroll
        for (int kk = 0; kk < 2; kk++) {
            bf16x8 a[2], b[4];
#pragma unroll
            for (int mi = 0; mi < 2; mi++) {
                int row = w * 32 + mi * 16 + c16;
                int p = (kk * 4 + quad) ^ (row & 7);
                a[mi] = *(const bf16x8*)(Ash[cur] + row * 64 + p * 8);
            }
#pragma unroll
            for (int ni = 0; ni < 4; ni++) {
                int row = ni * 16 + c16;
                int p = (kk * 4 + quad) ^ (row & 7);
                b[ni] = *(const bf16x8*)(Bsh[cur] + row * 64 + p * 8);
            }
#pragma unroll
            for (int mi = 0; mi < 2; mi++)
#pragma unroll
                for (int ni = 0; ni < 4; ni++)
                    acc[mi][ni] = __builtin_amdgcn_mfma_f32_16x16x32_bf16(a[mi], b[ni], acc[mi][ni], 0, 0, 0);
        }
        __syncthreads();
    }
    if (z < 2) {
        u16* out = (z == 0) ? Qm : Km;
        int Mact = (z == 0) ? NQ : SREAL;
#pragma unroll
        for (int mi = 0; mi < 2; mi++)
#pragma unroll
            for (int ni = 0; ni < 4; ni++) {
                int n = n0 + ni * 16 + c16;
                float bval = bias[n] * bscale;
#pragma unroll
                for (int r = 0; r < 4; r++) {
                    int m = m0 + w * 32 + mi * 16 + quad * 4 + r;
                    float val = (m < Mact) ? (acc[mi][ni][r] + bval) : 0.f;
                    out[(size_t)m * DDIM + n] = f2bf(val);
                }
            }
    } else {
#pragma unroll
        for (int mi = 0; mi < 2; mi++)
#pragma unroll
            for (int ni = 0; ni < 4; ni++) {
                int n = n0 + ni * 16 + c16;
                float bval = bias[n];
                int mbase = m0 + w * 32 + mi * 16 + quad * 4;
                ushort4 o;
                o.x = (mbase + 0 < SREAL) ? f2bf(acc[mi][ni][0] + bval) : (u16)0;
                o.y = (mbase + 1 < SREAL) ? f2bf(acc[mi][ni][1] + bval) : (u16)0;
                o.z = (mbase + 2 < SREAL) ? f2bf(acc[mi][ni][2] + bval) : (u16)0;
                o.w = (mbase + 3 < SREAL) ? f2bf(acc[mi][ni][3] + bval) : (u16)0;
                *(ushort4*)(VmT + (size_t)n * SPAD + mbase) = o;
            }
    }
}

// ---------------- split-S flash attention, no-max softmax, 64-s chunks ----------------
__global__ __launch_bounds__(256, 4) void attn_kernel(
    const u16* __restrict__ Qm, const u16* __restrict__ Km, const u16* __restrict__ VmT,
    const int* __restrict__ bank_mask,
    u16* __restrict__ Opart, float* __restrict__ Lpart)
{
    __shared__ __align__(16) u16 SH[64 * 64 * 3];   // K | V^T | P
    __shared__ float mk[64];
    u16* Ksh = SH;
    u16* Vsh = SH + 4096;
    u16* Psh = SH + 8192;
    int b = blockIdx.x;
    int xcd = b & 7, j = b >> 3;
    int grp = xcd * 6 + (j >> 5);         // grp = sp*NHEAD + h
    int qt = j & 31;
    int sp = grp / NHEAD, h = grp - sp * NHEAD;
    int q0 = qt * 64;
    int t = threadIdx.x, w = t >> 6, l = t & 63, quad = l >> 4, c16 = l & 15;

    bf16x8 qf[2];
#pragma unroll
    for (int kk = 0; kk < 2; kk++) {
        int row = q0 + w * 16 + c16;
        qf[kk] = *(const bf16x8*)(Qm + (size_t)row * DDIM + h * EDIM + kk * 32 + quad * 8);
    }
    bf16x8 ones;
#pragma unroll
    for (int i = 0; i < 8; i++) ones[i] = (__bf16)1.0f;

    f32x4 zz = {0.f, 0.f, 0.f, 0.f};
    f32x4 of[4], ol;
#pragma unroll
    for (int nei = 0; nei < 4; nei++) of[nei] = zz;
    ol = zz;

    for (int sc = 0; sc < 8; sc++) {
        int s0 = sp * 512 + sc * 64;
#pragma unroll
        for (int i = 0; i < 2; i++) {
            int ch = i * 256 + t;
            int r = ch >> 3, pc = ch & 7, jc = pc ^ (r & 7);
            async16(Km + (size_t)(s0 + r) * DDIM + h * EDIM + jc * 8, (char*)Ksh + ch * 16);
        }
#pragma unroll
        for (int i = 0; i < 2; i++) {
            int ch = i * 256 + t;
            int e = ch >> 3, pc = ch & 7, jc = pc ^ (e & 7);
            async16(VmT + (size_t)(h * EDIM + e) * SPAD + s0 + jc * 8, (char*)Vsh + ch * 16);
        }
        if (t < 64) {
            int s = s0 + t;
            mk[t] = (s < SREAL && bank_mask[s] != 0) ? 1.f : 0.f;
        }
        __syncthreads();

        f32x4 sacc[4];
#pragma unroll
        for (int ni = 0; ni < 4; ni++) sacc[ni] = zz;
#pragma unroll
        for (int kk = 0; kk < 2; kk++) {
            bf16x8 kb[4];
#pragma unroll
            for (int ni = 0; ni < 4; ni++) {
                int row = ni * 16 + c16;
                int p = (kk * 4 + quad) ^ (row & 7);
                kb[ni] = *(const bf16x8*)(Ksh + row * 64 + p * 8);
            }
#pragma unroll
            for (int ni = 0; ni < 4; ni++)
                sacc[ni] = __builtin_amdgcn_mfma_f32_16x16x32_bf16(qf[kk], kb[ni], sacc[ni], 0, 0, 0);
        }
        float m01[4];
#pragma unroll
        for (int ni = 0; ni < 4; ni++) m01[ni] = mk[ni * 16 + c16];
#pragma unroll
        for (int ni = 0; ni < 4; ni++)
#pragma unroll
            for (int r = 0; r < 4; r++)
                sacc[ni][r] = __expf(sacc[ni][r]) * m01[ni];

#pragma unroll
        for (int ni = 0; ni < 4; ni++)
#pragma unroll
            for (int r = 0; r < 4; r++) {
                int row = w * 16 + quad * 4 + r;
                int col = ni * 16 + c16;
                int p = (col >> 3) ^ (row & 7);
                Psh[row * 64 + p * 8 + (col & 7)] = f2bf(sacc[ni][r]);
            }

#pragma unroll
        for (int kk = 0; kk < 2; kk++) {
            bf16x8 pa, vb[4];
            {
                int row = w * 16 + c16;
                int p = (kk * 4 + quad) ^ (row & 7);
                pa = *(const bf16x8*)(Psh + row * 64 + p * 8);
            }
#pragma unroll
            for (int nei = 0; nei < 4; nei++) {
                int e = nei * 16 + c16;
                int p = (kk * 4 + quad) ^ (e & 7);
                vb[nei] = *(const bf16x8*)(Vsh + e * 64 + p * 8);
            }
#pragma unroll
            for (int nei = 0; nei < 4; nei++)
                of[nei] = __builtin_amdgcn_mfma_f32_16x16x32_bf16(pa, vb[nei], of[nei], 0, 0, 0);
            ol = __builtin_amdgcn_mfma_f32_16x16x32_bf16(pa, ones, ol, 0, 0, 0);
        }
        __syncthreads();
    }

    // epilogue: transpose O through LDS (per-wave slice), store coalesced bf16
    float* Ost = (float*)SH + w * (16 * 68);
#pragma unroll
    for (int nei = 0; nei < 4; nei++)
#pragma unroll
        for (int r = 0; r < 4; r++)
            Ost[(quad * 4 + r) * 68 + nei * 16 + c16] = of[nei][r];
    int qq = l >> 2, cc = (l & 3) ^ (qq & 3);
    int base = grp * 32 + qt;
    uint4 packed[2];
    u16* pk = (u16*)packed;
#pragma unroll
    for (int jj = 0; jj < 4; jj++) {
        f32x4 v = *(const f32x4*)(Ost + qq * 68 + cc * 16 + jj * 4);
        pk[jj * 4 + 0] = f2bf(v[0]); pk[jj * 4 + 1] = f2bf(v[1]);
        pk[jj * 4 + 2] = f2bf(v[2]); pk[jj * 4 + 3] = f2bf(v[3]);
    }
    {
        u16* dst = Opart + (size_t)base * 4096 + (w * 16 + qq) * 64 + cc * 16;
        *(uint4*)dst = packed[0];
        *(uint4*)(dst + 8) = packed[1];
    }
    if (c16 == 0) {
#pragma unroll
        for (int r = 0; r < 4; r++) {
            int rin = w * 16 + quad * 4 + r;
            Lpart[(size_t)base * 64 + rin] = ol[r];
        }
    }
}

// ---------------- combine partials + mean-pool over TQ -> pooled (bf16) ----------------
__global__ __launch_bounds__(256) void combine_kernel(
    const u16* __restrict__ Opart, const float* __restrict__ Lpart,
    u16* __restrict__ pooledb)
{
    int gi = blockIdx.x * 4 + (threadIdx.x >> 6);   // 0..3071
    int e = threadIdx.x & 63;
    int lq = gi / NHEAD, h = gi - lq * NHEAD;
    float acc = 0.f;
#pragma unroll
    for (int row = 0; row < 8; row++) {
        int qrow = lq * 8 + row;
        int qt = qrow >> 6, rin = qrow & 63;
        float Ls = 0.f, val = 0.f;
#pragma unroll
        for (int sp = 0; sp < NSPLIT; sp++) {
            int base = (sp * NHEAD + h) * 32 + qt;
            Ls += Lpart[(size_t)base * 64 + rin];
            val += bf2f(Opart[(size_t)base * 4096 + rin * 64 + e]);
        }
        acc += val / Ls;
    }
    pooledb[(size_t)lq * DDIM + h * EDIM + e] = f2bf(acc * 0.125f);
}

// ---------------- final GEMM y = pooled(256,768) @ Wo(768,768)^T + bo, bf16 MFMA ----------------
__global__ __launch_bounds__(256) void wo_kernel(
    const u16* __restrict__ pb, const u16* __restrict__ Wob,
    const float* __restrict__ bo, float* __restrict__ y)
{
    __shared__ u16 Ash[64 * 128];
    __shared__ u16 Bsh[64 * 128];
    int m0 = blockIdx.x * 64, n0 = blockIdx.y * 64;
    int t = threadIdx.x, w = t >> 6, l = t & 63, quad = l >> 4, c16 = l & 15;

    f32x4 acc[4];
    f32x4 zz = {0.f, 0.f, 0.f, 0.f};
#pragma unroll
    for (int ni = 0; ni < 4; ni++) acc[ni] = zz;

    for (int kt = 0; kt < 6; kt++) {
        int k0 = kt * 128;
#pragma unroll
        for (int i = 0; i < 4; i++) {
            int ch = i * 256 + t;
            int r = ch >> 4, pc = ch & 15, jc = pc ^ (r & 15);
            async16(pb + (size_t)(m0 + r) * DDIM + k0 + jc * 8, (char*)Ash + ch * 16);
            async16(Wob + (size_t)(n0 + r) * DDIM + k0 + jc * 8, (char*)Bsh + ch * 16);
        }
        __syncthreads();
#pragma unroll
        for (int kk = 0; kk < 4; kk++) {
            int p = (kk * 4 + quad) ^ c16;
            bf16x8 a = *(const bf16x8*)(Ash + (w * 16 + c16) * 128 + p * 8);
            bf16x8 b[4];
#pragma unroll
            for (int ni = 0; ni < 4; ni++)
                b[ni] = *(const bf16x8*)(Bsh + (ni * 16 + c16) * 128 + p * 8);
#pragma unroll
            for (int ni = 0; ni < 4; ni++)
                acc[ni] = __builtin_amdgcn_mfma_f32_16x16x32_bf16(a, b[ni], acc[ni], 0, 0, 0);
        }
        __syncthreads();
    }
#pragma unroll
    for (int ni = 0; ni < 4; ni++) {
        int n = n0 + ni * 16 + c16;
        float bval = bo[n];
#pragma unroll
        for (int r = 0; r < 4; r++) {
            int m = m0 + w * 16 + quad * 4 + r;
            y[(size_t)m * DDIM + n] = acc[ni][r] + bval;
        }
    }
}

extern "C" void kernel_launch(void* const* d_in, const int* in_sizes, int n_in,
                              void* d_out, int out_size, void* d_ws, size_t ws_size,
                              hipStream_t stream)
{
    const float* tgt     = (const float*)d_in[0];
    const float* keyb    = (const float*)d_in[1];
    const float* valb    = (const float*)d_in[2];
    const int*   mask    = (const int*)d_in[3];
    const float* Wq      = (const float*)d_in[4];
    const float* bq      = (const float*)d_in[5];
    const float* Wk      = (const float*)d_in[6];
    const float* bk      = (const float*)d_in[7];
    const float* Wv      = (const float*)d_in[8];
    const float* bv      = (const float*)d_in[9];
    const float* Wo      = (const float*)d_in[10];
    const float* bo      = (const float*)d_in[11];
    const float* g_q     = (const float*)d_in[12];
    const float* beta_q  = (const float*)d_in[13];
    const float* g_kv    = (const float*)d_in[14];
    const float* beta_kv = (const float*)d_in[15];
    float* y = (float*)d_out;

    char* ws = (char*)d_ws;
    // persistent:
    u16* Qm  = (u16*)(ws + 0);           // 3,145,728
    u16* Km  = (u16*)(ws + 3145728);     // 3,145,728
    u16* VmT = (u16*)(ws + 6291456);     // 3,145,728
    u16* Wob = (u16*)(ws + 9437184);     // 1,179,648
    // phase A (dead after proj_kernel):
    u16* lnQ = (u16*)(ws + 10616832);
    u16* lnK = (u16*)(ws + 13762560);
    u16* lnV = (u16*)(ws + 16908288);
    u16* Wqb = (u16*)(ws + 20054016);
    u16* Wkb = (u16*)(ws + 21233664);
    u16* Wvb = (u16*)(ws + 22413312);    // ends 23,592,960
    // phase B (aliases phase A region):
    u16*   Opart   = (u16*)(ws + 10616832);   // 12,582,912 -> ends 23,199,744
    float* Lpart   = (float*)(ws + 23592960); // 393,216
    u16*   pooledb = (u16*)(ws + 23986176);   // 393,216

    hipLaunchKernelGGL(prep_kernel, dim3(3840), dim3(256), 0, stream,
                       Wq, Wk, Wv, Wo, Wqb, Wkb, Wvb, Wob,
                       tgt, keyb, valb, g_q, beta_q, g_kv, beta_kv, lnQ, lnK, lnV);
    hipLaunchKernelGGL(proj_kernel, dim3(12, 16, 3), dim3(256), 0, stream,
                       lnQ, lnK, lnV, Wqb, Wkb, Wvb, bq, bk, bv, Qm, Km, VmT);
    hipLaunchKernelGGL(attn_kernel, dim3(1536), dim3(256), 0, stream,
                       Qm, Km, VmT, mask, Opart, Lpart);
    hipLaunchKernelGGL(combine_kernel, dim3(768), dim3(256), 0, stream,
                       Opart, Lpart, pooledb);
    hipLaunchKernelGGL(wo_kernel, dim3(4, 12), dim3(256), 0, stream,
                       pooledb, Wob, bo, y);
}